// Round 4
// baseline (295.681 us; speedup 1.0000x reference)
//
#include <hip/hip_runtime.h>

#define N_NODES 50000
#define N_EDGES 800000
#define DIM 128
#define NUM_REL 200
#define NREL2 (2 * NUM_REL)
#define SCAN_BLK 512
#define SCAN_NBLK ((N_NODES + SCAN_BLK - 1) / SCAN_BLK)  // 98

// ---------------------------------------------------------------------------
// Kernel A: merged relation table R[400][128] (W_O rel-half for t<200, W_I
// rel-half else, + matching bias) and rel_new output (rel_emb @ W_R^T + b_R).
// ---------------------------------------------------------------------------
__global__ void rel_tables_kernel(const float* __restrict__ rel_emb,
                                  const float* __restrict__ W_O_w,
                                  const float* __restrict__ W_O_b,
                                  const float* __restrict__ W_I_w,
                                  const float* __restrict__ W_I_b,
                                  const float* __restrict__ W_R_w,
                                  const float* __restrict__ W_R_b,
                                  float* __restrict__ R,
                                  float* __restrict__ rel_new) {
    __shared__ float row[DIM];
    const int t = blockIdx.x;   // 0..399
    const int j = threadIdx.x;  // 0..127
    row[j] = rel_emb[t * DIM + j];
    __syncthreads();

    const bool fwd = (t < NUM_REL);
    const float* __restrict__ wSel = (fwd ? W_O_w : W_I_w) + j * (2 * DIM);
    const float* __restrict__ wR = W_R_w + j * DIM;

    float aSel = 0.f, aR = 0.f;
#pragma unroll 8
    for (int k = 0; k < DIM; ++k) {
        const float e = row[k];
        aSel += e * wSel[k];
        aR += e * wR[k];
    }
    R[t * DIM + j] = aSel + (fwd ? W_O_b[j] : W_I_b[j]);
    rel_new[t * DIM + j] = aR + W_R_b[j];
}

// ---------------------------------------------------------------------------
// Kernel B (v3): per-node tables. 384 threads/block = (matrix sel × 128 cols),
// 16 nodes/block, 16 accumulators/thread (register-resident: ~16+8+4 live).
//   sel 0: EE[n]       = ent_emb[n] @ (ent-half of W_O)^T
//   sel 1: EE[50000+n] = ent_emb[n] @ (ent-half of W_I)^T
//   sel 2: ent_S[n]    = ent_emb[n] @ W_S^T + b_S
// Wave-uniform branches (128-col splits align with 64-lane waves). LDS node
// rows are uniform-address broadcasts (0 bank conflicts).
// N_NODES = 3125 * 16 exactly -> no bounds checks.
// ---------------------------------------------------------------------------
#define REP16(F) F(0) F(1) F(2) F(3) F(4) F(5) F(6) F(7) \
                 F(8) F(9) F(10) F(11) F(12) F(13) F(14) F(15)

__global__ void __launch_bounds__(384)
node_tables_kernel(const float* __restrict__ ent_emb,
                   const float* __restrict__ W_O_w,
                   const float* __restrict__ W_I_w,
                   const float* __restrict__ W_S_w,
                   const float* __restrict__ W_S_b,
                   float* __restrict__ EE,
                   float* __restrict__ ent_S) {
    __shared__ float rows[16][DIM];  // 8 KB
    const int t = threadIdx.x;       // 0..383
    const int n0 = blockIdx.x * 16;

    // Stage 16 node rows = 512 float4, coalesced.
    float* L = &rows[0][0];
    {
        const int fi = t;  // 0..383
        const int n = n0 + (fi >> 5);
        *(float4*)(L + fi * 4) = *(const float4*)(ent_emb + (size_t)n * DIM + (fi & 31) * 4);
    }
    if (t < 128) {
        const int fi = 384 + t;
        const int n = n0 + (fi >> 5);
        *(float4*)(L + fi * 4) = *(const float4*)(ent_emb + (size_t)n * DIM + (fi & 31) * 4);
    }
    __syncthreads();

    // Per-thread weight row + output base (wave-uniform select).
    const int j = t & 127;
    const float* wrow;
    float* outp;
    float bias = 0.f;
    if (t < 128) {
        wrow = W_O_w + j * (2 * DIM) + DIM;
        outp = EE + j;
    } else if (t < 256) {
        wrow = W_I_w + j * (2 * DIM) + DIM;
        outp = EE + (size_t)N_NODES * DIM + j;
    } else {
        wrow = W_S_w + j * DIM;
        outp = ent_S + j;
        bias = W_S_b[j];
    }

#define DECL(m) float a##m = 0.f;
    REP16(DECL)
#undef DECL

#pragma unroll 2
    for (int k4 = 0; k4 < DIM / 4; ++k4) {
        const float4 w = *(const float4*)(wrow + k4 * 4);
#define STEP(m)                                                         \
        {                                                               \
            const float4 e = *(const float4*)(L + (m) * DIM + k4 * 4);  \
            a##m += e.x * w.x + e.y * w.y + e.z * w.z + e.w * w.w;      \
        }
        REP16(STEP)
#undef STEP
    }

#define STORE(m) outp[(size_t)(n0 + (m)) * DIM] = a##m + bias;
    REP16(STORE)
#undef STORE
}

// ---------------------------------------------------------------------------
// CSR construction: histogram -> 3-phase exclusive scan -> fill.
// ---------------------------------------------------------------------------
__global__ void __launch_bounds__(256)
hist_kernel(const int* __restrict__ dst, int* __restrict__ counts) {
    const int e = blockIdx.x * 256 + threadIdx.x;
    if (e < N_EDGES) atomicAdd(&counts[dst[e]], 1);
}

__global__ void __launch_bounds__(SCAN_BLK)
scan1_kernel(const int* __restrict__ counts, int* __restrict__ offs,
             int* __restrict__ bsum) {
    __shared__ int tmp[SCAN_BLK];
    const int i = blockIdx.x * SCAN_BLK + threadIdx.x;
    const int v = (i < N_NODES) ? counts[i] : 0;
    tmp[threadIdx.x] = v;
    __syncthreads();
    for (int off = 1; off < SCAN_BLK; off <<= 1) {
        const int t = (threadIdx.x >= off) ? tmp[threadIdx.x - off] : 0;
        __syncthreads();
        tmp[threadIdx.x] += t;
        __syncthreads();
    }
    if (i < N_NODES) offs[i] = tmp[threadIdx.x] - v;  // exclusive
    if (threadIdx.x == SCAN_BLK - 1) bsum[blockIdx.x] = tmp[SCAN_BLK - 1];
}

__global__ void scan2_kernel(int* __restrict__ bsum) {
    if (threadIdx.x == 0 && blockIdx.x == 0) {
        int a = 0;
        for (int i = 0; i < SCAN_NBLK; ++i) {
            const int t = bsum[i];
            bsum[i] = a;
            a += t;
        }
    }
}

__global__ void __launch_bounds__(SCAN_BLK)
scan3_kernel(int* __restrict__ offs, const int* __restrict__ bsum) {
    const int i = blockIdx.x * SCAN_BLK + threadIdx.x;
    if (i < N_NODES) offs[i] += bsum[blockIdx.x];
}

// Fill: sorted-by-dst packed edge payload: row(17b) | etype<<17 (9b).
__global__ void __launch_bounds__(256)
fill_kernel(const int* __restrict__ src, const int* __restrict__ dst,
            const int* __restrict__ et, const int* __restrict__ offs,
            int* __restrict__ cursor, int* __restrict__ sp) {
    const int e = blockIdx.x * 256 + threadIdx.x;
    if (e >= N_EDGES) return;
    const int d = dst[e];
    const int t = et[e];
    const int row = src[e] + ((t < NUM_REL) ? 0 : N_NODES);
    const int pos = atomicAdd(&cursor[d], 1);
    sp[offs[d] + pos] = row | (t << 17);
}

// ---------------------------------------------------------------------------
// Gather-reduce: one wave per node. Lane l owns output floats [2l, 2l+1].
// Fuses finalize: out = ent_S + acc / max(deg,1).  (Unchanged this round —
// next round's counters will expose its bottleneck.)
// ---------------------------------------------------------------------------
__global__ void __launch_bounds__(256)
gather_kernel(const int* __restrict__ offs, const int* __restrict__ counts,
              const int* __restrict__ sp, const float* __restrict__ EE,
              const float* __restrict__ R, const float* __restrict__ ent_S,
              float* __restrict__ out_ent) {
    const int node = blockIdx.x * 4 + (threadIdx.x >> 6);
    if (node >= N_NODES) return;
    const int l = threadIdx.x & 63;

    const int beg = offs[node];
    const int cnt = counts[node];

    float ax = 0.f, ay = 0.f;
    for (int base = 0; base < cnt; base += 64) {
        const int kk = min(64, cnt - base);
        const int myp = (base + l < cnt) ? sp[beg + base + l] : 0;
#pragma unroll 4
        for (int i = 0; i < kk; ++i) {
            const int p = __shfl(myp, i);
            const int row = p & 0x1FFFF;
            const int t = p >> 17;
            const float2 e = *(const float2*)(EE + (size_t)row * DIM + 2 * l);
            const float2 r = *(const float2*)(R + (size_t)t * DIM + 2 * l);
            ax += e.x + r.x;
            ay += e.y + r.y;
        }
    }

    const float inv = 1.0f / fmaxf((float)cnt, 1.0f);
    const float2 s = *(const float2*)(ent_S + (size_t)node * DIM + 2 * l);
    float2 o;
    o.x = s.x + ax * inv;
    o.y = s.y + ay * inv;
    *(float2*)(out_ent + (size_t)node * DIM + 2 * l) = o;
}

extern "C" void kernel_launch(void* const* d_in, const int* in_sizes, int n_in,
                              void* d_out, int out_size, void* d_ws, size_t ws_size,
                              hipStream_t stream) {
    const int* src = (const int*)d_in[0];
    const int* dst = (const int*)d_in[1];
    const int* et = (const int*)d_in[2];
    const float* ent_emb = (const float*)d_in[3];
    const float* rel_emb = (const float*)d_in[4];
    const float* W_O_w = (const float*)d_in[5];
    const float* W_O_b = (const float*)d_in[6];
    const float* W_I_w = (const float*)d_in[7];
    const float* W_I_b = (const float*)d_in[8];
    const float* W_S_w = (const float*)d_in[9];
    const float* W_S_b = (const float*)d_in[10];
    const float* W_R_w = (const float*)d_in[11];
    const float* W_R_b = (const float*)d_in[12];

    float* out_ent = (float*)d_out;                    // [50000*128]
    float* out_rel = out_ent + (size_t)N_NODES * DIM;  // [400*128]

    // Workspace layout: R | EE | ent_S | counts,cursor | bsum | offs | sp
    float* wsf = (float*)d_ws;
    float* R = wsf;
    wsf += (size_t)NREL2 * DIM;          // 51,200 f
    float* EE = wsf;
    wsf += (size_t)2 * N_NODES * DIM;    // 12.8M f
    float* ent_S = wsf;
    wsf += (size_t)N_NODES * DIM;        // 6.4M f
    int* counts = (int*)wsf;
    int* cursor = counts + N_NODES;
    int* bsum = cursor + N_NODES;
    int* offs = bsum + 128;
    int* sp = offs + N_NODES;
    // total ~80.8 MB

    hipMemsetAsync(counts, 0, 2 * N_NODES * sizeof(int), stream);

    rel_tables_kernel<<<NREL2, DIM, 0, stream>>>(rel_emb, W_O_w, W_O_b, W_I_w, W_I_b,
                                                 W_R_w, W_R_b, R, out_rel);

    node_tables_kernel<<<N_NODES / 16, 384, 0, stream>>>(
        ent_emb, W_O_w, W_I_w, W_S_w, W_S_b, EE, ent_S);

    hist_kernel<<<(N_EDGES + 255) / 256, 256, 0, stream>>>(dst, counts);
    scan1_kernel<<<SCAN_NBLK, SCAN_BLK, 0, stream>>>(counts, offs, bsum);
    scan2_kernel<<<1, 64, 0, stream>>>(bsum);
    scan3_kernel<<<SCAN_NBLK, SCAN_BLK, 0, stream>>>(offs, bsum);
    fill_kernel<<<(N_EDGES + 255) / 256, 256, 0, stream>>>(src, dst, et, offs, cursor, sp);

    gather_kernel<<<(N_NODES + 3) / 4, 256, 0, stream>>>(offs, counts, sp, EE, R, ent_S,
                                                         out_ent);
}